// Round 8
// baseline (384.736 us; speedup 1.0000x reference)
//
#include <hip/hip_runtime.h>

#define D 64
#define SH 8   // XCD shards

typedef unsigned long long u64;
typedef unsigned short u16;

__device__ __forceinline__ float uaf(unsigned u) { return __uint_as_float(u); }

// pack two floats -> one uint of 2 bf16 (RNE)
__device__ __forceinline__ unsigned pkbf(float lo, float hi) {
    unsigned ul = __float_as_uint(lo);
    unsigned uh = __float_as_uint(hi);
    ul = (ul + 0x7fffu + ((ul >> 16) & 1u)) >> 16;
    uh = (uh + 0x7fffu + ((uh >> 16) & 1u)) & 0xffff0000u;
    return ul | uh;
}

// ---------------------------------------------------------------------------
// K-1: f32 -> bf16 row conversion (8 floats/thread)
// ---------------------------------------------------------------------------
__global__ __launch_bounds__(256) void k_cvt(
    const float4* __restrict__ X4, uint4* __restrict__ Xb4, int total)
{
    int i = blockIdx.x * 256 + threadIdx.x;
    if (i >= total) return;
    float4 a = X4[i * 2], b = X4[i * 2 + 1];
    uint4 o;
    o.x = pkbf(a.x, a.y); o.y = pkbf(a.z, a.w);
    o.z = pkbf(b.x, b.y); o.w = pkbf(b.z, b.w);
    Xb4[i] = o;
}

// ---------------------------------------------------------------------------
// K0: Ttw[which][j] = sum_k tw[a][k] * W[base+k][j]  for both layers
// ---------------------------------------------------------------------------
__global__ __launch_bounds__(256) void k_ttw(
    const float* __restrict__ tw1, const float* __restrict__ W1, float* __restrict__ T1,
    const float* __restrict__ tw2, const float* __restrict__ W2, float* __restrict__ T2)
{
    const float* tw = blockIdx.x ? tw2 : tw1;
    const float* W  = blockIdx.x ? W2  : W1;
    float*       T  = blockIdx.x ? T2  : T1;
    int t = threadIdx.x;
    int j = t & 63;
    int which = t >> 6;
    int a = which & 1;
    int base = (which < 2) ? 64 : 192;
    float s = 0.f;
    #pragma unroll 8
    for (int k = 0; k < 64; ++k)
        s += tw[a * 64 + k] * W[(base + k) * 64 + j];
    T[which * 64 + j] = s;
}

// ---------------------------------------------------------------------------
// K1: per-(shard,node) packed count+label atomic; shard s handled by blocks
// with blockIdx%8==s -> XCD-local atomic lines. [cnt:10|q0:27|q1:27]
// ---------------------------------------------------------------------------
__global__ __launch_bounds__(256) void k_count(
    const int* __restrict__ row, const int* __restrict__ col,
    const float* __restrict__ el,
    u64* __restrict__ packR, u64* __restrict__ packC, int E, int N, int SH_SZ)
{
    int s = blockIdx.x & (SH - 1);
    int j = blockIdx.x >> 3;
    int ebase = s * SH_SZ;
    int ssz = min(SH_SZ, E - ebase);
    int idx = j * 256 + threadIdx.x;
    if (idx >= ssz) return;
    int e = ebase + idx;
    int r = row[e], c = col[e];
    float2 lab = ((const float2*)el)[e];
    u64 q0 = (u64)(unsigned)(lab.x * 65536.0f);
    u64 q1 = (u64)(unsigned)(lab.y * 65536.0f);
    u64 p = (1ULL << 54) | (q0 << 27) | q1;
    atomicAdd(&packR[(size_t)s * N + r], p);
    atomicAdd(&packC[(size_t)s * N + c], p);
}

// ---------------------------------------------------------------------------
// K2: per-shard segment allocation. 16 wave-scans, then ONE parallel atomic
// round per block on 16 line-padded counters. Emits sub-cursors, deg-packs,
// stats.
// ---------------------------------------------------------------------------
__global__ __launch_bounds__(256) void k_prep(
    const u64* __restrict__ packR, const u64* __restrict__ packC,
    int* __restrict__ curR, int* __restrict__ curC,
    u64* __restrict__ degpackR, u64* __restrict__ degpackC,
    float* __restrict__ stats, int* __restrict__ gcur, int N, int SH_SZ)
{
    __shared__ int lds_tot[4][16];
    __shared__ int lds_base[4][16];

    int n = blockIdx.x * 256 + threadIdx.x;
    int lane = threadIdx.x & 63;
    int wv = threadIdx.x >> 6;
    const u64 LOW54 = (1ULL << 54) - 1;
    int cr[SH], cc[SH], psR[SH], psC[SH];
    u64 TR = 0, TC = 0;
    #pragma unroll
    for (int s = 0; s < SH; ++s) {
        u64 pR = (n < N) ? packR[(size_t)s * N + n] : 0;
        u64 pC = (n < N) ? packC[(size_t)s * N + n] : 0;
        cr[s] = (int)(pR >> 54); TR += pR & LOW54;
        cc[s] = (int)(pC >> 54); TC += pC & LOW54;
    }
    #pragma unroll
    for (int s = 0; s < SH; ++s) {
        int ps = cr[s];
        #pragma unroll
        for (int d2 = 1; d2 < 64; d2 <<= 1) { int t2 = __shfl_up(ps, d2); if (lane >= d2) ps += t2; }
        psR[s] = ps;
        int ps2 = cc[s];
        #pragma unroll
        for (int d2 = 1; d2 < 64; d2 <<= 1) { int t2 = __shfl_up(ps2, d2); if (lane >= d2) ps2 += t2; }
        psC[s] = ps2;
        if (lane == 63) { lds_tot[wv][s] = ps; lds_tot[wv][8 + s] = ps2; }
    }
    __syncthreads();
    if (wv == 0 && lane < 16) {
        int t0 = lds_tot[0][lane], t1 = lds_tot[1][lane],
            t2 = lds_tot[2][lane], t3 = lds_tot[3][lane];
        int gb = atomicAdd(&gcur[lane * 32], t0 + t1 + t2 + t3);
        lds_base[0][lane] = gb;
        lds_base[1][lane] = gb + t0;
        lds_base[2][lane] = gb + t0 + t1;
        lds_base[3][lane] = gb + t0 + t1 + t2;
    }
    __syncthreads();

    if (n < N) {
        u64 dpR = 0, dpC = 0;
        int tr = 0, tc = 0;
        #pragma unroll
        for (int s = 0; s < SH; ++s) {
            curR[(size_t)s * N + n] = s * SH_SZ + lds_base[wv][s]     + psR[s] - cr[s];
            curC[(size_t)s * N + n] = s * SH_SZ + lds_base[wv][8 + s] + psC[s] - cc[s];
            dpR |= ((u64)cr[s]) << (8 * s); tr += cr[s];
            dpC |= ((u64)cc[s]) << (8 * s); tc += cc[s];
        }
        degpackR[n] = dpR;
        degpackC[n] = dpC;
        const u64 M27 = (1ULL << 27) - 1;
        const float qs = 1.0f / 65536.0f;
        float sr0 = (float)((TR >> 27) & M27) * qs;
        float sr1 = (float)(TR & M27) * qs;
        float sc0 = (float)((TC >> 27) & M27) * qs;
        float sc1 = (float)(TC & M27) * qs;
        float ir = 1.0f / fmaxf((float)tr, 1.0f);
        float ic = 1.0f / fmaxf((float)tc, 1.0f);
        float* sN = stats + (size_t)n * 8;
        sN[0] = ir;        sN[1] = ic;
        sN[2] = sr0 * ir;  sN[3] = sr1 * ir;
        sN[4] = sc0 * ic;  sN[5] = sc1 * ic;
        sN[6] = (float)tr; sN[7] = (float)tc;
    }
}

// ---------------------------------------------------------------------------
// K3: sharded bucket fill — cursors and staging region XCD-local.
// ---------------------------------------------------------------------------
__global__ __launch_bounds__(256) void k_fill(
    const int* __restrict__ row, const int* __restrict__ col,
    int* __restrict__ curR, int* __restrict__ curC,
    int* __restrict__ stageR, int* __restrict__ stageC, int E, int N, int SH_SZ)
{
    int s = blockIdx.x & (SH - 1);
    int j = blockIdx.x >> 3;
    int ebase = s * SH_SZ;
    int ssz = min(SH_SZ, E - ebase);
    int idx = j * 256 + threadIdx.x;
    if (idx >= ssz) return;
    int e = ebase + idx;
    int r = row[e], c = col[e];
    stageR[atomicAdd(&curR[(size_t)s * N + r], 1)] = c;
    stageC[atomicAdd(&curC[(size_t)s * N + c], 1)] = r;
}

// ---------------------------------------------------------------------------
// 8-segment bf16 gather: 8 neighbors/iteration (8 lanes x 16B = full 128B row),
// branchless prefix-select over shards, f32 accumulation (acc statically
// indexed -> registers).
// ---------------------------------------------------------------------------
__device__ __forceinline__ void gather_side8(
    const int* __restrict__ stage, const int* __restrict__ cur, u64 dp,
    int n, int N, const uint4* __restrict__ xb4, int grp, int c8, float* acc)
{
    int d[SH], p[SH], st[SH];
    #pragma unroll
    for (int s = 0; s < SH; ++s) d[s] = (int)((dp >> (8 * s)) & 255);
    p[0] = 0;
    #pragma unroll
    for (int s = 1; s < SH; ++s) p[s] = p[s - 1] + d[s - 1];
    int deg = p[SH - 1] + d[SH - 1];
    #pragma unroll
    for (int s = 0; s < SH; ++s)
        st[s] = cur[(size_t)s * N + n] - d[s] - p[s];

    for (int k = 0; k < deg; k += 8) {
        int kk = k + grp;
        int addr = st[0] + kk;
        #pragma unroll
        for (int s = 1; s < SH; ++s)
            addr = (kk >= p[s]) ? st[s] + kk : addr;
        bool pv = kk < deg;
        int a = stage[pv ? addr : 0];
        uint4 v = xb4[(size_t)a * 8 + c8];
        if (pv) {
            acc[0] += uaf(v.x << 16); acc[1] += uaf(v.x & 0xffff0000u);
            acc[2] += uaf(v.y << 16); acc[3] += uaf(v.y & 0xffff0000u);
            acc[4] += uaf(v.z << 16); acc[5] += uaf(v.z & 0xffff0000u);
            acc[6] += uaf(v.w << 16); acc[7] += uaf(v.w & 0xffff0000u);
        }
    }
}

// ---------------------------------------------------------------------------
// K4: fused layer (bf16 features in, bf16 h out for layer1 / f32 for layer2).
// 512 threads, 16 nodes/block, 2 nodes/wave, 8 neighbors per wave-instruction.
// Phase B: h[128] @ W via b128 hs broadcasts + b32 Ws reads; rank-2 opinion
// epilogue. LDS 40KB.
// ---------------------------------------------------------------------------
__global__ __launch_bounds__(512) void k_layer(
    const u16* __restrict__ xb,
    const int* __restrict__ curR, const int* __restrict__ curC,
    const int* __restrict__ stageR, const int* __restrict__ stageC,
    const u64* __restrict__ degpackR, const u64* __restrict__ degpackC,
    const float* __restrict__ stats,
    const float* __restrict__ Ttw,   // [4][64]
    const float* __restrict__ W,     // [256][64]
    const float* __restrict__ b,     // [64]
    u16* __restrict__ yb, float* __restrict__ yf, int N)
{
    __shared__ float4 hs4[16][32];
    __shared__ float  Ws[128 * 64];

    const uint4* xb4 = (const uint4*)xb;

    int t    = threadIdx.x;
    int lane = t & 63;
    int wv   = t >> 6;
    int c8   = lane & 7;
    int grp  = lane >> 3;
    int base = blockIdx.x * 16;

    float sf[2][4];

    #pragma unroll
    for (int i = 0; i < 2; ++i) {
        int loc = wv * 2 + i;
        int n   = base + loc;
        float aR[8] = {0.f,0.f,0.f,0.f,0.f,0.f,0.f,0.f};
        float aC[8] = {0.f,0.f,0.f,0.f,0.f,0.f,0.f,0.f};
        float ir = 0.f, ic = 0.f;
        sf[i][0] = sf[i][1] = sf[i][2] = sf[i][3] = 0.f;
        if (n < N) {
            const float4* st = (const float4*)(stats + (size_t)n * 8);
            float4 sA = st[0];
            float4 sB = st[1];
            ir = sA.x; ic = sA.y;
            sf[i][0] = sA.z; sf[i][1] = sA.w;
            sf[i][2] = sB.x; sf[i][3] = sB.y;
            gather_side8(stageR, curR, degpackR[n], n, N, xb4, grp, c8, aR);
            gather_side8(stageC, curC, degpackC[n], n, N, xb4, grp, c8, aC);
        }
        #pragma unroll
        for (int o = 8; o < 64; o <<= 1) {
            #pragma unroll
            for (int q = 0; q < 8; ++q) {
                aR[q] += __shfl_xor(aR[q], o);
                aC[q] += __shfl_xor(aC[q], o);
            }
        }
        if (grp == 0) {
            hs4[loc][c8 * 2]     = make_float4(aR[0]*ir, aR[1]*ir, aR[2]*ir, aR[3]*ir);
            hs4[loc][c8 * 2 + 1] = make_float4(aR[4]*ir, aR[5]*ir, aR[6]*ir, aR[7]*ir);
            hs4[loc][16 + c8*2]     = make_float4(aC[0]*ic, aC[1]*ic, aC[2]*ic, aC[3]*ic);
            hs4[loc][16 + c8*2 + 1] = make_float4(aC[4]*ic, aC[5]*ic, aC[6]*ic, aC[7]*ic);
        }
    }

    __syncthreads();
    #pragma unroll
    for (int i = 0; i < 16; ++i) {
        int L = i * 512 + t;
        Ws[L] = W[L + ((L < 4096) ? 0 : 4096)];
    }
    __syncthreads();

    // Phase B: b128 broadcast reads of h, b32 conflict-free reads of Ws
    const float4* hA = hs4[wv * 2];
    const float4* hB = hs4[wv * 2 + 1];
    float a0 = 0.f, a1 = 0.f;
    #pragma unroll 8
    for (int j4 = 0; j4 < 32; ++j4) {
        float4 h0 = hA[j4];
        float4 h1 = hB[j4];
        const float* wp = &Ws[j4 * 256 + lane];
        float w0 = wp[0], w1 = wp[64], w2 = wp[128], w3 = wp[192];
        a0 += h0.x * w0 + h0.y * w1 + h0.z * w2 + h0.w * w3;
        a1 += h1.x * w0 + h1.y * w1 + h1.z * w2 + h1.w * w3;
    }

    float tR0 = Ttw[lane],       tR1 = Ttw[64 + lane];
    float tC0 = Ttw[128 + lane], tC1 = Ttw[192 + lane];
    float bias = b[lane];
    float vv[2] = {a0, a1};
    #pragma unroll
    for (int i = 0; i < 2; ++i) {
        int n = base + wv * 2 + i;
        if (n < N) {
            float v = vv[i] + sf[i][0] * tR0 + sf[i][1] * tR1
                            + sf[i][2] * tC0 + sf[i][3] * tC1 + bias;
            v = fmaxf(v, 0.0f);
            if (yf) {
                yf[(size_t)n * D + lane] = v;
            } else {
                unsigned u = __float_as_uint(v);
                yb[(size_t)n * D + lane] = (u16)((u + 0x7fffu + ((u >> 16) & 1u)) >> 16);
            }
        }
    }
}

// ---------------------------------------------------------------------------
extern "C" void kernel_launch(void* const* d_in, const int* in_sizes, int n_in,
                              void* d_out, int out_size, void* d_ws, size_t ws_size,
                              hipStream_t stream)
{
    const float* X   = (const float*)d_in[0];
    const int*   ei  = (const int*)  d_in[1];
    const float* el  = (const float*)d_in[2];
    const float* w1  = (const float*)d_in[3];
    const float* tw1 = (const float*)d_in[4];
    const float* b1  = (const float*)d_in[5];
    const float* w2  = (const float*)d_in[6];
    const float* tw2 = (const float*)d_in[7];
    const float* b2  = (const float*)d_in[8];
    float* out = (float*)d_out;

    int N = in_sizes[0] / D;     // 50000
    int E = in_sizes[1] / 2;     // 800000
    const int* row = ei;
    const int* col = ei + E;
    int SH_SZ = (E + SH - 1) / SH;

    // Workspace (~24.9 MB). pack region reused as staging CSR after k_prep.
    size_t packBytes = (size_t)2 * SH * N * sizeof(u64);
    size_t stageBytes = (size_t)2 * E * sizeof(int);
    if (stageBytes > packBytes) packBytes = stageBytes;

    char* wsb = (char*)d_ws;
    u64*   packR    = (u64*)wsb;                        // SH*N u64 (zeroed)
    u64*   packC    = packR + (size_t)SH * N;           // SH*N u64 (zeroed)
    int*   stageR   = (int*)wsb;                        // E ints (aliases pack)
    int*   stageC   = stageR + E;                       // E ints
    int*   gcur     = (int*)(wsb + packBytes);          // 512 ints line-padded (zeroed)
    int*   curR     = gcur + 512;                       // SH*N
    int*   curC     = curR + (size_t)SH * N;            // SH*N
    u64*   degpackR = (u64*)(curC + (size_t)SH * N);    // N
    u64*   degpackC = degpackR + N;                     // N
    float* stats    = (float*)(degpackC + N);           // 8N
    float* Ttw1     = stats + (size_t)8 * N;            // 256
    float* Ttw2     = Ttw1 + 256;                       // 256
    u16*   Xb       = (u16*)(Ttw2 + 256);               // 64N bf16
    u16*   h1b      = Xb + (size_t)64 * N;              // 64N bf16

    (void)hipMemsetAsync(packR, 0, (size_t)2 * SH * N * sizeof(u64), stream);
    (void)hipMemsetAsync(gcur, 0, 512 * sizeof(int), stream);

    k_cvt<<<(N * 8 + 255) / 256, 256, 0, stream>>>((const float4*)X, (uint4*)Xb, N * 8);
    k_ttw<<<2, 256, 0, stream>>>(tw1, w1, Ttw1, tw2, w2, Ttw2);

    int SB = SH * ((SH_SZ + 255) / 256);
    int NB = (N + 255) / 256;
    int LB = (N + 15) / 16;

    k_count<<<SB, 256, 0, stream>>>(row, col, el, packR, packC, E, N, SH_SZ);
    k_prep<<<NB, 256, 0, stream>>>(packR, packC, curR, curC,
                                   degpackR, degpackC, stats, gcur, N, SH_SZ);
    k_fill<<<SB, 256, 0, stream>>>(row, col, curR, curC, stageR, stageC, E, N, SH_SZ);

    // layer 1: Xb -> h1b (bf16); layer 2: h1b -> out (f32)
    k_layer<<<LB, 512, 0, stream>>>(Xb, curR, curC, stageR, stageC,
                                    degpackR, degpackC, stats,
                                    Ttw1, w1, b1, h1b, nullptr, N);
    k_layer<<<LB, 512, 0, stream>>>(h1b, curR, curC, stageR, stageC,
                                    degpackR, degpackC, stats,
                                    Ttw2, w2, b2, nullptr, out, N);
}

// Round 9
// 345.142 us; speedup vs baseline: 1.1147x; 1.1147x over previous
//
#include <hip/hip_runtime.h>

#define D 64
#define SH 8   // XCD shards

typedef unsigned long long u64;

// ---------------------------------------------------------------------------
// K0: Ttw[which][j] = sum_k tw[a][k] * W[base+k][j]  for both layers
// ---------------------------------------------------------------------------
__global__ __launch_bounds__(256) void k_ttw(
    const float* __restrict__ tw1, const float* __restrict__ W1, float* __restrict__ T1,
    const float* __restrict__ tw2, const float* __restrict__ W2, float* __restrict__ T2)
{
    const float* tw = blockIdx.x ? tw2 : tw1;
    const float* W  = blockIdx.x ? W2  : W1;
    float*       T  = blockIdx.x ? T2  : T1;
    int t = threadIdx.x;
    int j = t & 63;
    int which = t >> 6;
    int a = which & 1;
    int base = (which < 2) ? 64 : 192;
    float s = 0.f;
    #pragma unroll 8
    for (int k = 0; k < 64; ++k)
        s += tw[a * 64 + k] * W[(base + k) * 64 + j];
    T[which * 64 + j] = s;
}

// ---------------------------------------------------------------------------
// K1: per-(shard,node) packed count+label atomic; shard s handled by blocks
// with blockIdx%8==s -> XCD-local atomic lines. [cnt:10|q0:27|q1:27]
// ---------------------------------------------------------------------------
__global__ __launch_bounds__(256) void k_count(
    const int* __restrict__ row, const int* __restrict__ col,
    const float* __restrict__ el,
    u64* __restrict__ packR, u64* __restrict__ packC, int E, int N, int SH_SZ)
{
    int s = blockIdx.x & (SH - 1);
    int j = blockIdx.x >> 3;
    int ebase = s * SH_SZ;
    int ssz = min(SH_SZ, E - ebase);
    int idx = j * 256 + threadIdx.x;
    if (idx >= ssz) return;
    int e = ebase + idx;
    int r = row[e], c = col[e];
    float2 lab = ((const float2*)el)[e];
    u64 q0 = (u64)(unsigned)(lab.x * 65536.0f);
    u64 q1 = (u64)(unsigned)(lab.y * 65536.0f);
    u64 p = (1ULL << 54) | (q0 << 27) | q1;
    atomicAdd(&packR[(size_t)s * N + r], p);
    atomicAdd(&packC[(size_t)s * N + c], p);
}

// ---------------------------------------------------------------------------
// K2: per-shard segment allocation. 16 wave-scans, then ONE parallel atomic
// round per block on 16 line-padded counters. Emits sub-cursors, deg-packs,
// stats.
// ---------------------------------------------------------------------------
__global__ __launch_bounds__(256) void k_prep(
    const u64* __restrict__ packR, const u64* __restrict__ packC,
    int* __restrict__ curR, int* __restrict__ curC,
    u64* __restrict__ degpackR, u64* __restrict__ degpackC,
    float* __restrict__ stats, int* __restrict__ gcur, int N, int SH_SZ)
{
    __shared__ int lds_tot[4][16];
    __shared__ int lds_base[4][16];

    int n = blockIdx.x * 256 + threadIdx.x;
    int lane = threadIdx.x & 63;
    int wv = threadIdx.x >> 6;
    const u64 LOW54 = (1ULL << 54) - 1;
    int cr[SH], cc[SH], psR[SH], psC[SH];
    u64 TR = 0, TC = 0;
    #pragma unroll
    for (int s = 0; s < SH; ++s) {
        u64 pR = (n < N) ? packR[(size_t)s * N + n] : 0;
        u64 pC = (n < N) ? packC[(size_t)s * N + n] : 0;
        cr[s] = (int)(pR >> 54); TR += pR & LOW54;
        cc[s] = (int)(pC >> 54); TC += pC & LOW54;
    }
    #pragma unroll
    for (int s = 0; s < SH; ++s) {
        int ps = cr[s];
        #pragma unroll
        for (int d2 = 1; d2 < 64; d2 <<= 1) { int t2 = __shfl_up(ps, d2); if (lane >= d2) ps += t2; }
        psR[s] = ps;
        int ps2 = cc[s];
        #pragma unroll
        for (int d2 = 1; d2 < 64; d2 <<= 1) { int t2 = __shfl_up(ps2, d2); if (lane >= d2) ps2 += t2; }
        psC[s] = ps2;
        if (lane == 63) { lds_tot[wv][s] = ps; lds_tot[wv][8 + s] = ps2; }
    }
    __syncthreads();
    if (wv == 0 && lane < 16) {
        int t0 = lds_tot[0][lane], t1 = lds_tot[1][lane],
            t2 = lds_tot[2][lane], t3 = lds_tot[3][lane];
        int gb = atomicAdd(&gcur[lane * 32], t0 + t1 + t2 + t3);
        lds_base[0][lane] = gb;
        lds_base[1][lane] = gb + t0;
        lds_base[2][lane] = gb + t0 + t1;
        lds_base[3][lane] = gb + t0 + t1 + t2;
    }
    __syncthreads();

    if (n < N) {
        u64 dpR = 0, dpC = 0;
        int tr = 0, tc = 0;
        #pragma unroll
        for (int s = 0; s < SH; ++s) {
            curR[(size_t)s * N + n] = s * SH_SZ + lds_base[wv][s]     + psR[s] - cr[s];
            curC[(size_t)s * N + n] = s * SH_SZ + lds_base[wv][8 + s] + psC[s] - cc[s];
            dpR |= ((u64)cr[s]) << (8 * s); tr += cr[s];
            dpC |= ((u64)cc[s]) << (8 * s); tc += cc[s];
        }
        degpackR[n] = dpR;
        degpackC[n] = dpC;
        const u64 M27 = (1ULL << 27) - 1;
        const float qs = 1.0f / 65536.0f;
        float sr0 = (float)((TR >> 27) & M27) * qs;
        float sr1 = (float)(TR & M27) * qs;
        float sc0 = (float)((TC >> 27) & M27) * qs;
        float sc1 = (float)(TC & M27) * qs;
        float ir = 1.0f / fmaxf((float)tr, 1.0f);
        float ic = 1.0f / fmaxf((float)tc, 1.0f);
        float* sN = stats + (size_t)n * 8;
        sN[0] = ir;        sN[1] = ic;
        sN[2] = sr0 * ir;  sN[3] = sr1 * ir;
        sN[4] = sc0 * ic;  sN[5] = sc1 * ic;
        sN[6] = (float)tr; sN[7] = (float)tc;
    }
}

// ---------------------------------------------------------------------------
// K3: sharded bucket fill — cursors and staging region XCD-local.
// ---------------------------------------------------------------------------
__global__ __launch_bounds__(256) void k_fill(
    const int* __restrict__ row, const int* __restrict__ col,
    int* __restrict__ curR, int* __restrict__ curC,
    int* __restrict__ stageR, int* __restrict__ stageC, int E, int N, int SH_SZ)
{
    int s = blockIdx.x & (SH - 1);
    int j = blockIdx.x >> 3;
    int ebase = s * SH_SZ;
    int ssz = min(SH_SZ, E - ebase);
    int idx = j * 256 + threadIdx.x;
    if (idx >= ssz) return;
    int e = ebase + idx;
    int r = row[e], c = col[e];
    stageR[atomicAdd(&curR[(size_t)s * N + r], 1)] = c;
    stageC[atomicAdd(&curC[(size_t)s * N + c], 1)] = r;
}

// ---------------------------------------------------------------------------
// Interleaved 2-stream gather (R and C sides of one node advance together):
// each iteration issues 2 independent index loads + 2 independent 256B row
// loads -> ~2x memory-level parallelism vs sequential side loops, and the
// per-wave dependent-chain depth drops from (degR+degC)/4 to max(degR,degC)/4.
// Branchless prefix-select over the 8 shard segments, per-stream predication.
// ---------------------------------------------------------------------------
__device__ __forceinline__ void gather_two(
    const int* __restrict__ stageR, const int* __restrict__ curR, u64 dpR,
    const int* __restrict__ stageC, const int* __restrict__ curC, u64 dpC,
    int n, int N, const float4* __restrict__ x4, int grp, int c4,
    float4& outR, float4& outC)
{
    int dR[SH], pR[SH], stR[SH];
    int dC[SH], pC[SH], stC[SH];
    #pragma unroll
    for (int s = 0; s < SH; ++s) {
        dR[s] = (int)((dpR >> (8 * s)) & 255);
        dC[s] = (int)((dpC >> (8 * s)) & 255);
    }
    pR[0] = 0; pC[0] = 0;
    #pragma unroll
    for (int s = 1; s < SH; ++s) {
        pR[s] = pR[s - 1] + dR[s - 1];
        pC[s] = pC[s - 1] + dC[s - 1];
    }
    int degR = pR[SH - 1] + dR[SH - 1];
    int degC = pC[SH - 1] + dC[SH - 1];
    #pragma unroll
    for (int s = 0; s < SH; ++s) {
        stR[s] = curR[(size_t)s * N + n] - dR[s] - pR[s];
        stC[s] = curC[(size_t)s * N + n] - dC[s] - pC[s];
    }

    float4 aR = make_float4(0.f, 0.f, 0.f, 0.f);
    float4 aC = make_float4(0.f, 0.f, 0.f, 0.f);
    int m = max(degR, degC);
    for (int k = 0; k < m; k += 4) {
        int kk = k + grp;
        int adR = stR[0] + kk;
        int adC = stC[0] + kk;
        #pragma unroll
        for (int s = 1; s < SH; ++s) {
            adR = (kk >= pR[s]) ? stR[s] + kk : adR;
            adC = (kk >= pC[s]) ? stC[s] + kk : adC;
        }
        bool vR = kk < degR;
        bool vC = kk < degC;
        int aIR = stageR[vR ? adR : 0];
        int aIC = stageC[vC ? adC : 0];
        float4 xR = x4[(size_t)aIR * 16 + c4];
        float4 xC = x4[(size_t)aIC * 16 + c4];
        if (vR) { aR.x += xR.x; aR.y += xR.y; aR.z += xR.z; aR.w += xR.w; }
        if (vC) { aC.x += xC.x; aC.y += xC.y; aC.z += xC.z; aC.w += xC.w; }
    }
    outR = aR; outC = aC;
}

// ---------------------------------------------------------------------------
// K4: fused layer. 512 threads, 16 nodes/block, 2 nodes/wave; interleaved
// float4 gathers (2 streams x 4 neighbors per iteration), cross-group shfl
// reduce, h[128] @ W + rank-2 opinion epilogue. LDS 40KB -> 32 waves/CU.
// ---------------------------------------------------------------------------
__global__ __launch_bounds__(512) void k_layer(
    const float* __restrict__ x,
    const int* __restrict__ curR, const int* __restrict__ curC,
    const int* __restrict__ stageR, const int* __restrict__ stageC,
    const u64* __restrict__ degpackR, const u64* __restrict__ degpackC,
    const float* __restrict__ stats,
    const float* __restrict__ Ttw,   // [4][64]
    const float* __restrict__ W,     // [256][64]
    const float* __restrict__ b,     // [64]
    float* __restrict__ y, int N)
{
    __shared__ float4 hs4[16][32];
    __shared__ float  Ws[128 * 64];

    const float4* x4 = (const float4*)x;

    int t    = threadIdx.x;
    int lane = t & 63;
    int wv   = t >> 6;
    int c4   = lane & 15;
    int grp  = lane >> 4;
    int base = blockIdx.x * 16;

    float sf[2][4];

    #pragma unroll
    for (int i = 0; i < 2; ++i) {
        int loc = wv * 2 + i;
        int n   = base + loc;
        float4 accR = make_float4(0.f, 0.f, 0.f, 0.f);
        float4 accC = make_float4(0.f, 0.f, 0.f, 0.f);
        float ir = 0.f, ic = 0.f;
        sf[i][0] = sf[i][1] = sf[i][2] = sf[i][3] = 0.f;
        if (n < N) {
            const float4* st = (const float4*)(stats + (size_t)n * 8);
            float4 sA = st[0];
            float4 sB = st[1];
            ir = sA.x; ic = sA.y;
            sf[i][0] = sA.z; sf[i][1] = sA.w;
            sf[i][2] = sB.x; sf[i][3] = sB.y;
            gather_two(stageR, curR, degpackR[n],
                       stageC, curC, degpackC[n],
                       n, N, x4, grp, c4, accR, accC);
        }
        #pragma unroll
        for (int o = 16; o < 64; o <<= 1) {
            accR.x += __shfl_xor(accR.x, o); accR.y += __shfl_xor(accR.y, o);
            accR.z += __shfl_xor(accR.z, o); accR.w += __shfl_xor(accR.w, o);
            accC.x += __shfl_xor(accC.x, o); accC.y += __shfl_xor(accC.y, o);
            accC.z += __shfl_xor(accC.z, o); accC.w += __shfl_xor(accC.w, o);
        }
        if (grp == 0) {
            hs4[loc][c4]      = make_float4(accR.x * ir, accR.y * ir, accR.z * ir, accR.w * ir);
            hs4[loc][16 + c4] = make_float4(accC.x * ic, accC.y * ic, accC.z * ic, accC.w * ic);
        }
    }

    __syncthreads();
    #pragma unroll
    for (int i = 0; i < 16; ++i) {
        int L = i * 512 + t;
        Ws[L] = W[L + ((L < 4096) ? 0 : 4096)];
    }
    __syncthreads();

    const float* hsf = (const float*)hs4;
    int r0 = (wv * 2) * 128, r1 = r0 + 128;
    float a0 = 0.f, a1 = 0.f;
    #pragma unroll 8
    for (int j = 0; j < 128; ++j) {
        float wj = Ws[j * 64 + lane];
        a0 += hsf[r0 + j] * wj;
        a1 += hsf[r1 + j] * wj;
    }

    float tR0 = Ttw[lane],       tR1 = Ttw[64 + lane];
    float tC0 = Ttw[128 + lane], tC1 = Ttw[192 + lane];
    float bias = b[lane];
    float vv[2] = {a0, a1};
    #pragma unroll
    for (int i = 0; i < 2; ++i) {
        int n = base + wv * 2 + i;
        if (n < N) {
            float v = vv[i] + sf[i][0] * tR0 + sf[i][1] * tR1
                            + sf[i][2] * tC0 + sf[i][3] * tC1 + bias;
            y[(size_t)n * D + lane] = fmaxf(v, 0.0f);
        }
    }
}

// ---------------------------------------------------------------------------
extern "C" void kernel_launch(void* const* d_in, const int* in_sizes, int n_in,
                              void* d_out, int out_size, void* d_ws, size_t ws_size,
                              hipStream_t stream)
{
    const float* X   = (const float*)d_in[0];
    const int*   ei  = (const int*)  d_in[1];
    const float* el  = (const float*)d_in[2];
    const float* w1  = (const float*)d_in[3];
    const float* tw1 = (const float*)d_in[4];
    const float* b1  = (const float*)d_in[5];
    const float* w2  = (const float*)d_in[6];
    const float* tw2 = (const float*)d_in[7];
    const float* b2  = (const float*)d_in[8];
    float* out = (float*)d_out;

    int N = in_sizes[0] / D;     // 50000
    int E = in_sizes[1] / 2;     // 800000
    const int* row = ei;
    const int* col = ei + E;
    int SH_SZ = (E + SH - 1) / SH;

    // Workspace (~24.8 MB). pack region reused as staging CSR after k_prep.
    size_t packBytes = (size_t)2 * SH * N * sizeof(u64);
    size_t stageBytes = (size_t)2 * E * sizeof(int);
    if (stageBytes > packBytes) packBytes = stageBytes;

    char* wsb = (char*)d_ws;
    u64*   packR    = (u64*)wsb;                        // SH*N u64 (zeroed)
    u64*   packC    = packR + (size_t)SH * N;           // SH*N u64 (zeroed)
    int*   stageR   = (int*)wsb;                        // E ints (aliases pack)
    int*   stageC   = stageR + E;                       // E ints
    int*   gcur     = (int*)(wsb + packBytes);          // 512 ints, line-padded (zeroed)
    int*   curR     = gcur + 512;                       // SH*N
    int*   curC     = curR + (size_t)SH * N;            // SH*N
    u64*   degpackR = (u64*)(curC + (size_t)SH * N);    // N
    u64*   degpackC = degpackR + N;                     // N
    float* stats    = (float*)(degpackC + N);           // 8N
    float* Ttw1     = stats + (size_t)8 * N;            // 256
    float* Ttw2     = Ttw1 + 256;                       // 256
    float* h1       = Ttw2 + 256;                       // 64N

    (void)hipMemsetAsync(packR, 0, (size_t)2 * SH * N * sizeof(u64), stream);
    (void)hipMemsetAsync(gcur, 0, 512 * sizeof(int), stream);

    k_ttw<<<2, 256, 0, stream>>>(tw1, w1, Ttw1, tw2, w2, Ttw2);

    int SB = SH * ((SH_SZ + 255) / 256);
    int NB = (N + 255) / 256;
    int LB = (N + 15) / 16;

    k_count<<<SB, 256, 0, stream>>>(row, col, el, packR, packC, E, N, SH_SZ);
    k_prep<<<NB, 256, 0, stream>>>(packR, packC, curR, curC,
                                   degpackR, degpackC, stats, gcur, N, SH_SZ);
    k_fill<<<SB, 256, 0, stream>>>(row, col, curR, curC, stageR, stageC, E, N, SH_SZ);

    k_layer<<<LB, 512, 0, stream>>>(X, curR, curC, stageR, stageC,
                                    degpackR, degpackC, stats,
                                    Ttw1, w1, b1, h1, N);
    k_layer<<<LB, 512, 0, stream>>>(h1, curR, curC, stageR, stageC,
                                    degpackR, degpackC, stats,
                                    Ttw2, w2, b2, out, N);
}

// Round 10
// 336.113 us; speedup vs baseline: 1.1447x; 1.0269x over previous
//
#include <hip/hip_runtime.h>

#define D 64
#define SH 8   // XCD shards

typedef unsigned long long u64;
typedef unsigned short u16;

__device__ __forceinline__ float uaf(unsigned u) { return __uint_as_float(u); }

__device__ __forceinline__ unsigned pkbf(float lo, float hi) {
    unsigned ul = __float_as_uint(lo);
    unsigned uh = __float_as_uint(hi);
    ul = (ul + 0x7fffu + ((ul >> 16) & 1u)) >> 16;
    uh = (uh + 0x7fffu + ((uh >> 16) & 1u)) & 0xffff0000u;
    return ul | uh;
}

// ---------------------------------------------------------------------------
// K-1: f32 -> bf16 conversion (8 floats/thread)
// ---------------------------------------------------------------------------
__global__ __launch_bounds__(256) void k_cvt(
    const float4* __restrict__ X4, uint4* __restrict__ Xb4, int total)
{
    int i = blockIdx.x * 256 + threadIdx.x;
    if (i >= total) return;
    float4 a = X4[i * 2], b = X4[i * 2 + 1];
    uint4 o;
    o.x = pkbf(a.x, a.y); o.y = pkbf(a.z, a.w);
    o.z = pkbf(b.x, b.y); o.w = pkbf(b.z, b.w);
    Xb4[i] = o;
}

// ---------------------------------------------------------------------------
// K0: Ttw[which][j] = sum_k tw[a][k] * W[base+k][j]  for both layers
// ---------------------------------------------------------------------------
__global__ __launch_bounds__(256) void k_ttw(
    const float* __restrict__ tw1, const float* __restrict__ W1, float* __restrict__ T1,
    const float* __restrict__ tw2, const float* __restrict__ W2, float* __restrict__ T2)
{
    const float* tw = blockIdx.x ? tw2 : tw1;
    const float* W  = blockIdx.x ? W2  : W1;
    float*       T  = blockIdx.x ? T2  : T1;
    int t = threadIdx.x;
    int j = t & 63;
    int which = t >> 6;
    int a = which & 1;
    int base = (which < 2) ? 64 : 192;
    float s = 0.f;
    #pragma unroll 8
    for (int k = 0; k < 64; ++k)
        s += tw[a * 64 + k] * W[(base + k) * 64 + j];
    T[which * 64 + j] = s;
}

// ---------------------------------------------------------------------------
// K1: per-(shard,node) packed count+label atomic; shard s handled by blocks
// with blockIdx%8==s -> XCD-local atomic lines. [cnt:10|q0:27|q1:27]
// ---------------------------------------------------------------------------
__global__ __launch_bounds__(256) void k_count(
    const int* __restrict__ row, const int* __restrict__ col,
    const float* __restrict__ el,
    u64* __restrict__ packR, u64* __restrict__ packC, int E, int N, int SH_SZ)
{
    int s = blockIdx.x & (SH - 1);
    int j = blockIdx.x >> 3;
    int ebase = s * SH_SZ;
    int ssz = min(SH_SZ, E - ebase);
    int idx = j * 256 + threadIdx.x;
    if (idx >= ssz) return;
    int e = ebase + idx;
    int r = row[e], c = col[e];
    float2 lab = ((const float2*)el)[e];
    u64 q0 = (u64)(unsigned)(lab.x * 65536.0f);
    u64 q1 = (u64)(unsigned)(lab.y * 65536.0f);
    u64 p = (1ULL << 54) | (q0 << 27) | q1;
    atomicAdd(&packR[(size_t)s * N + r], p);
    atomicAdd(&packC[(size_t)s * N + c], p);
}

// ---------------------------------------------------------------------------
// K2: per-shard segment allocation (16 scans) + compact CSR offsets (2 more
// scans of total degree). ONE parallel atomic round per block on 18
// line-padded counters. Emits sub-cursors, deg-packs, compact offs, stats.
// ---------------------------------------------------------------------------
__global__ __launch_bounds__(256) void k_prep(
    const u64* __restrict__ packR, const u64* __restrict__ packC,
    int* __restrict__ curR, int* __restrict__ curC,
    u64* __restrict__ degpackR, u64* __restrict__ degpackC,
    int* __restrict__ off_row, int* __restrict__ off_col,
    float* __restrict__ stats, int* __restrict__ gcur, int N, int SH_SZ)
{
    __shared__ int lds_tot[4][18];
    __shared__ int lds_base[4][18];

    int n = blockIdx.x * 256 + threadIdx.x;
    int lane = threadIdx.x & 63;
    int wv = threadIdx.x >> 6;
    const u64 LOW54 = (1ULL << 54) - 1;
    int cr[SH], cc[SH], psR[SH], psC[SH];
    u64 TR = 0, TC = 0;
    #pragma unroll
    for (int s = 0; s < SH; ++s) {
        u64 pR = (n < N) ? packR[(size_t)s * N + n] : 0;
        u64 pC = (n < N) ? packC[(size_t)s * N + n] : 0;
        cr[s] = (int)(pR >> 54); TR += pR & LOW54;
        cc[s] = (int)(pC >> 54); TC += pC & LOW54;
    }
    int tr = 0, tc = 0;
    #pragma unroll
    for (int s = 0; s < SH; ++s) { tr += cr[s]; tc += cc[s]; }

    #pragma unroll
    for (int s = 0; s < SH; ++s) {
        int ps = cr[s];
        #pragma unroll
        for (int d2 = 1; d2 < 64; d2 <<= 1) { int t2 = __shfl_up(ps, d2); if (lane >= d2) ps += t2; }
        psR[s] = ps;
        int ps2 = cc[s];
        #pragma unroll
        for (int d2 = 1; d2 < 64; d2 <<= 1) { int t2 = __shfl_up(ps2, d2); if (lane >= d2) ps2 += t2; }
        psC[s] = ps2;
        if (lane == 63) { lds_tot[wv][s] = ps; lds_tot[wv][8 + s] = ps2; }
    }
    // scans of total degree for compact CSR offsets
    int psT = tr, psU = tc;
    #pragma unroll
    for (int d2 = 1; d2 < 64; d2 <<= 1) {
        int t2 = __shfl_up(psT, d2);
        int t3 = __shfl_up(psU, d2);
        if (lane >= d2) { psT += t2; psU += t3; }
    }
    if (lane == 63) { lds_tot[wv][16] = psT; lds_tot[wv][17] = psU; }
    __syncthreads();
    if (wv == 0 && lane < 18) {
        int t0 = lds_tot[0][lane], t1 = lds_tot[1][lane],
            t2 = lds_tot[2][lane], t3 = lds_tot[3][lane];
        int gb = atomicAdd(&gcur[lane * 32], t0 + t1 + t2 + t3);
        lds_base[0][lane] = gb;
        lds_base[1][lane] = gb + t0;
        lds_base[2][lane] = gb + t0 + t1;
        lds_base[3][lane] = gb + t0 + t1 + t2;
    }
    __syncthreads();

    if (n < N) {
        u64 dpR = 0, dpC = 0;
        #pragma unroll
        for (int s = 0; s < SH; ++s) {
            curR[(size_t)s * N + n] = s * SH_SZ + lds_base[wv][s]     + psR[s] - cr[s];
            curC[(size_t)s * N + n] = s * SH_SZ + lds_base[wv][8 + s] + psC[s] - cc[s];
            dpR |= ((u64)cr[s]) << (8 * s);
            dpC |= ((u64)cc[s]) << (8 * s);
        }
        degpackR[n] = dpR;
        degpackC[n] = dpC;
        off_row[n] = lds_base[wv][16] + psT - tr;
        off_col[n] = lds_base[wv][17] + psU - tc;
        const u64 M27 = (1ULL << 27) - 1;
        const float qs = 1.0f / 65536.0f;
        float sr0 = (float)((TR >> 27) & M27) * qs;
        float sr1 = (float)(TR & M27) * qs;
        float sc0 = (float)((TC >> 27) & M27) * qs;
        float sc1 = (float)(TC & M27) * qs;
        float ir = 1.0f / fmaxf((float)tr, 1.0f);
        float ic = 1.0f / fmaxf((float)tc, 1.0f);
        float* sN = stats + (size_t)n * 8;
        sN[0] = ir;        sN[1] = ic;
        sN[2] = sr0 * ir;  sN[3] = sr1 * ir;
        sN[4] = sc0 * ic;  sN[5] = sc1 * ic;
        sN[6] = (float)tr; sN[7] = (float)tc;
    }
}

// ---------------------------------------------------------------------------
// K3: sharded bucket fill — cursors and staging region XCD-local.
// ---------------------------------------------------------------------------
__global__ __launch_bounds__(256) void k_fill(
    const int* __restrict__ row, const int* __restrict__ col,
    int* __restrict__ curR, int* __restrict__ curC,
    int* __restrict__ stageR, int* __restrict__ stageC, int E, int N, int SH_SZ)
{
    int s = blockIdx.x & (SH - 1);
    int j = blockIdx.x >> 3;
    int ebase = s * SH_SZ;
    int ssz = min(SH_SZ, E - ebase);
    int idx = j * 256 + threadIdx.x;
    if (idx >= ssz) return;
    int e = ebase + idx;
    int r = row[e], c = col[e];
    stageR[atomicAdd(&curR[(size_t)s * N + r], 1)] = c;
    stageC[atomicAdd(&curC[(size_t)s * N + c], 1)] = r;
}

// ---------------------------------------------------------------------------
// K3.5: compact the 8 sharded segments per node into a true CSR. One wave per
// node; lanes cover compact slots; shard found via prefix-select (cost paid
// ONCE here instead of every gather iteration). Writes fully coalesced.
// ---------------------------------------------------------------------------
__global__ __launch_bounds__(256) void k_reorder(
    const int* __restrict__ stageR, const int* __restrict__ stageC,
    const int* __restrict__ curR, const int* __restrict__ curC,
    const u64* __restrict__ degpackR, const u64* __restrict__ degpackC,
    const int* __restrict__ off_row, const int* __restrict__ off_col,
    int* __restrict__ nbrR, int* __restrict__ nbrC, int N)
{
    int n = blockIdx.x * 4 + (threadIdx.x >> 6);
    if (n >= N) return;
    int lane = threadIdx.x & 63;

    {
        u64 dp = degpackR[n];
        int d[SH], p[SH], st[SH];
        #pragma unroll
        for (int s = 0; s < SH; ++s) d[s] = (int)((dp >> (8 * s)) & 255);
        p[0] = 0;
        #pragma unroll
        for (int s = 1; s < SH; ++s) p[s] = p[s - 1] + d[s - 1];
        int deg = p[SH - 1] + d[SH - 1];
        #pragma unroll
        for (int s = 0; s < SH; ++s)
            st[s] = curR[(size_t)s * N + n] - d[s] - p[s];   // post-fill cur = seg_end
        int base = off_row[n];
        for (int k = lane; k < deg; k += 64) {
            int src = st[0] + k;
            #pragma unroll
            for (int s = 1; s < SH; ++s)
                src = (k >= p[s]) ? st[s] + k : src;
            nbrR[base + k] = stageR[src];
        }
    }
    {
        u64 dp = degpackC[n];
        int d[SH], p[SH], st[SH];
        #pragma unroll
        for (int s = 0; s < SH; ++s) d[s] = (int)((dp >> (8 * s)) & 255);
        p[0] = 0;
        #pragma unroll
        for (int s = 1; s < SH; ++s) p[s] = p[s - 1] + d[s - 1];
        int deg = p[SH - 1] + d[SH - 1];
        #pragma unroll
        for (int s = 0; s < SH; ++s)
            st[s] = curC[(size_t)s * N + n] - d[s] - p[s];
        int base = off_col[n];
        for (int k = lane; k < deg; k += 64) {
            int src = st[0] + k;
            #pragma unroll
            for (int s = 1; s < SH; ++s)
                src = (k >= p[s]) ? st[s] + k : src;
            nbrC[base + k] = stageC[src];
        }
    }
}

// ---------------------------------------------------------------------------
// K4: fused layer, compact CSR + bf16 features. 512 threads, 16 nodes/block,
// 2 nodes/wave; lane=(grp 0..3, c4 0..15): 4 neighbors x 16 lanes x 8B = one
// 512B wave-instruction; minimal registers (no shard tables). Cross-group
// shfl reduce; Phase B h[128] @ W (f32 LDS) + rank-2 opinion epilogue.
// Layer1 writes bf16 h, layer2 writes f32 out.
// ---------------------------------------------------------------------------
__global__ __launch_bounds__(512) void k_layer(
    const u16* __restrict__ xb,
    const int* __restrict__ off_row, const int* __restrict__ off_col,
    const int* __restrict__ nbrR, const int* __restrict__ nbrC,
    const float* __restrict__ stats,
    const float* __restrict__ Ttw,   // [4][64]
    const float* __restrict__ W,     // [256][64]
    const float* __restrict__ b,     // [64]
    u16* __restrict__ yb, float* __restrict__ yf, int N)
{
    __shared__ float4 hs4[16][32];
    __shared__ float  Ws[128 * 64];

    const uint2* xb2 = (const uint2*)xb;

    int t    = threadIdx.x;
    int lane = t & 63;
    int wv   = t >> 6;
    int c4   = lane & 15;
    int grp  = lane >> 4;
    int base = blockIdx.x * 16;

    float sf[2][4];

    #pragma unroll
    for (int i = 0; i < 2; ++i) {
        int loc = wv * 2 + i;
        int n   = base + loc;
        float4 aR = make_float4(0.f, 0.f, 0.f, 0.f);
        float4 aC = make_float4(0.f, 0.f, 0.f, 0.f);
        float ir = 0.f, ic = 0.f;
        sf[i][0] = sf[i][1] = sf[i][2] = sf[i][3] = 0.f;
        if (n < N) {
            const float4* st = (const float4*)(stats + (size_t)n * 8);
            float4 sA = st[0];
            float4 sB = st[1];
            ir = sA.x; ic = sA.y;
            sf[i][0] = sA.z; sf[i][1] = sA.w;
            sf[i][2] = sB.x; sf[i][3] = sB.y;
            int dR = (int)sB.z, dC = (int)sB.w;
            int sR = off_row[n], sC = off_col[n];
            for (int k = 0; k < dR; k += 4) {
                int kk = k + grp;
                bool pv = kk < dR;
                int a = nbrR[sR + (pv ? kk : 0)];
                uint2 v = xb2[(size_t)a * 16 + c4];
                if (pv) {
                    aR.x += uaf(v.x << 16); aR.y += uaf(v.x & 0xffff0000u);
                    aR.z += uaf(v.y << 16); aR.w += uaf(v.y & 0xffff0000u);
                }
            }
            for (int k = 0; k < dC; k += 4) {
                int kk = k + grp;
                bool pv = kk < dC;
                int a = nbrC[sC + (pv ? kk : 0)];
                uint2 v = xb2[(size_t)a * 16 + c4];
                if (pv) {
                    aC.x += uaf(v.x << 16); aC.y += uaf(v.x & 0xffff0000u);
                    aC.z += uaf(v.y << 16); aC.w += uaf(v.y & 0xffff0000u);
                }
            }
        }
        #pragma unroll
        for (int o = 16; o < 64; o <<= 1) {
            aR.x += __shfl_xor(aR.x, o); aR.y += __shfl_xor(aR.y, o);
            aR.z += __shfl_xor(aR.z, o); aR.w += __shfl_xor(aR.w, o);
            aC.x += __shfl_xor(aC.x, o); aC.y += __shfl_xor(aC.y, o);
            aC.z += __shfl_xor(aC.z, o); aC.w += __shfl_xor(aC.w, o);
        }
        if (grp == 0) {
            hs4[loc][c4]      = make_float4(aR.x * ir, aR.y * ir, aR.z * ir, aR.w * ir);
            hs4[loc][16 + c4] = make_float4(aC.x * ic, aC.y * ic, aC.z * ic, aC.w * ic);
        }
    }

    __syncthreads();
    #pragma unroll
    for (int i = 0; i < 16; ++i) {
        int L = i * 512 + t;
        Ws[L] = W[L + ((L < 4096) ? 0 : 4096)];
    }
    __syncthreads();

    const float* hsf = (const float*)hs4;
    int r0 = (wv * 2) * 128, r1 = r0 + 128;
    float a0 = 0.f, a1 = 0.f;
    #pragma unroll 8
    for (int j = 0; j < 128; ++j) {
        float wj = Ws[j * 64 + lane];
        a0 += hsf[r0 + j] * wj;
        a1 += hsf[r1 + j] * wj;
    }

    float tR0 = Ttw[lane],       tR1 = Ttw[64 + lane];
    float tC0 = Ttw[128 + lane], tC1 = Ttw[192 + lane];
    float bias = b[lane];
    float vv[2] = {a0, a1};
    #pragma unroll
    for (int i = 0; i < 2; ++i) {
        int n = base + wv * 2 + i;
        if (n < N) {
            float v = vv[i] + sf[i][0] * tR0 + sf[i][1] * tR1
                            + sf[i][2] * tC0 + sf[i][3] * tC1 + bias;
            v = fmaxf(v, 0.0f);
            if (yf) {
                yf[(size_t)n * D + lane] = v;
            } else {
                unsigned u = __float_as_uint(v);
                yb[(size_t)n * D + lane] = (u16)((u + 0x7fffu + ((u >> 16) & 1u)) >> 16);
            }
        }
    }
}

// ---------------------------------------------------------------------------
extern "C" void kernel_launch(void* const* d_in, const int* in_sizes, int n_in,
                              void* d_out, int out_size, void* d_ws, size_t ws_size,
                              hipStream_t stream)
{
    const float* X   = (const float*)d_in[0];
    const int*   ei  = (const int*)  d_in[1];
    const float* el  = (const float*)d_in[2];
    const float* w1  = (const float*)d_in[3];
    const float* tw1 = (const float*)d_in[4];
    const float* b1  = (const float*)d_in[5];
    const float* w2  = (const float*)d_in[6];
    const float* tw2 = (const float*)d_in[7];
    const float* b2  = (const float*)d_in[8];
    float* out = (float*)d_out;

    int N = in_sizes[0] / D;     // 50000
    int E = in_sizes[1] / 2;     // 800000
    const int* row = ei;
    const int* col = ei + E;
    int SH_SZ = (E + SH - 1) / SH;

    // Workspace (~25.2 MB). pack region -> stage CSR (after prep) -> h1 bf16
    // (after reorder). Each alias begins only after its predecessor is dead.
    size_t packBytes = (size_t)2 * SH * N * sizeof(u64);
    size_t stageBytes = (size_t)2 * E * sizeof(int);
    size_t h1Bytes = (size_t)64 * N * sizeof(u16);
    if (stageBytes > packBytes) packBytes = stageBytes;
    if (h1Bytes > packBytes) packBytes = h1Bytes;

    char* wsb = (char*)d_ws;
    u64*   packR    = (u64*)wsb;                        // SH*N u64 (zeroed)
    u64*   packC    = packR + (size_t)SH * N;           // SH*N u64 (zeroed)
    int*   stageR   = (int*)wsb;                        // E ints (aliases pack)
    int*   stageC   = stageR + E;                       // E ints
    u16*   h1b      = (u16*)wsb;                        // 64N bf16 (aliases stage)
    int*   gcur     = (int*)(wsb + packBytes);          // 1024 ints line-padded (zeroed)
    int*   curR     = gcur + 1024;                      // SH*N
    int*   curC     = curR + (size_t)SH * N;            // SH*N
    u64*   degpackR = (u64*)(curC + (size_t)SH * N);    // N
    u64*   degpackC = degpackR + N;                     // N
    int*   off_row  = (int*)(degpackC + N);             // N
    int*   off_col  = off_row + N;                      // N
    float* stats    = (float*)(off_col + N);            // 8N
    float* Ttw1     = stats + (size_t)8 * N;            // 256
    float* Ttw2     = Ttw1 + 256;                       // 256
    int*   nbrR     = (int*)(Ttw2 + 256);               // E
    int*   nbrC     = nbrR + E;                         // E
    u16*   Xb       = (u16*)(nbrC + E);                 // 64N bf16

    (void)hipMemsetAsync(packR, 0, (size_t)2 * SH * N * sizeof(u64), stream);
    (void)hipMemsetAsync(gcur, 0, 1024 * sizeof(int), stream);

    k_cvt<<<(N * 8 + 255) / 256, 256, 0, stream>>>((const float4*)X, (uint4*)Xb, N * 8);
    k_ttw<<<2, 256, 0, stream>>>(tw1, w1, Ttw1, tw2, w2, Ttw2);

    int SB = SH * ((SH_SZ + 255) / 256);
    int NB = (N + 255) / 256;
    int RB = (N + 3) / 4;
    int LB = (N + 15) / 16;

    k_count<<<SB, 256, 0, stream>>>(row, col, el, packR, packC, E, N, SH_SZ);
    k_prep<<<NB, 256, 0, stream>>>(packR, packC, curR, curC,
                                   degpackR, degpackC, off_row, off_col,
                                   stats, gcur, N, SH_SZ);
    k_fill<<<SB, 256, 0, stream>>>(row, col, curR, curC, stageR, stageC, E, N, SH_SZ);
    k_reorder<<<RB, 256, 0, stream>>>(stageR, stageC, curR, curC,
                                      degpackR, degpackC, off_row, off_col,
                                      nbrR, nbrC, N);

    // layer 1: Xb -> h1b (bf16, aliases dead stage region); layer 2 -> out f32
    k_layer<<<LB, 512, 0, stream>>>(Xb, off_row, off_col, nbrR, nbrC, stats,
                                    Ttw1, w1, b1, h1b, nullptr, N);
    k_layer<<<LB, 512, 0, stream>>>(h1b, off_row, off_col, nbrR, nbrC, stats,
                                    Ttw2, w2, b2, nullptr, out, N);
}

// Round 11
// 258.368 us; speedup vs baseline: 1.4891x; 1.3009x over previous
//
#include <hip/hip_runtime.h>

#define D 64
#define SH 8   // XCD shards

typedef unsigned long long u64;
typedef unsigned short u16;
typedef unsigned char u8;

__device__ __forceinline__ float uaf(unsigned u) { return __uint_as_float(u); }

__device__ __forceinline__ unsigned pkbf(float lo, float hi) {
    unsigned ul = __float_as_uint(lo);
    unsigned uh = __float_as_uint(hi);
    ul = (ul + 0x7fffu + ((ul >> 16) & 1u)) >> 16;
    uh = (uh + 0x7fffu + ((uh >> 16) & 1u)) & 0xffff0000u;
    return ul | uh;
}

// ---------------------------------------------------------------------------
// K-1: f32 -> bf16 conversion (8 floats/thread)
// ---------------------------------------------------------------------------
__global__ __launch_bounds__(256) void k_cvt(
    const float4* __restrict__ X4, uint4* __restrict__ Xb4, int total)
{
    int i = blockIdx.x * 256 + threadIdx.x;
    if (i >= total) return;
    float4 a = X4[i * 2], b = X4[i * 2 + 1];
    uint4 o;
    o.x = pkbf(a.x, a.y); o.y = pkbf(a.z, a.w);
    o.z = pkbf(b.x, b.y); o.w = pkbf(b.z, b.w);
    Xb4[i] = o;
}

// ---------------------------------------------------------------------------
// K0: Ttw[which][j] = sum_k tw[a][k] * W[base+k][j]  for both layers
// ---------------------------------------------------------------------------
__global__ __launch_bounds__(256) void k_ttw(
    const float* __restrict__ tw1, const float* __restrict__ W1, float* __restrict__ T1,
    const float* __restrict__ tw2, const float* __restrict__ W2, float* __restrict__ T2)
{
    const float* tw = blockIdx.x ? tw2 : tw1;
    const float* W  = blockIdx.x ? W2  : W1;
    float*       T  = blockIdx.x ? T2  : T1;
    int t = threadIdx.x;
    int j = t & 63;
    int which = t >> 6;
    int a = which & 1;
    int base = (which < 2) ? 64 : 192;
    float s = 0.f;
    #pragma unroll 8
    for (int k = 0; k < 64; ++k)
        s += tw[a * 64 + k] * W[(base + k) * 64 + j];
    T[which * 64 + j] = s;
}

// ---------------------------------------------------------------------------
// K1: per-(shard,node) packed count+label atomic (XCD-local lines). The
// returned old value's cnt field IS this edge's rank within its segment ->
// stored (u8, coalesced) so k_fill needs NO atomics. [cnt:10|q0:27|q1:27]
// ---------------------------------------------------------------------------
__global__ __launch_bounds__(256) void k_count(
    const int* __restrict__ row, const int* __restrict__ col,
    const float* __restrict__ el,
    u64* __restrict__ packR, u64* __restrict__ packC,
    u8* __restrict__ rankR, u8* __restrict__ rankC, int E, int N, int SH_SZ)
{
    int s = blockIdx.x & (SH - 1);
    int j = blockIdx.x >> 3;
    int ebase = s * SH_SZ;
    int ssz = min(SH_SZ, E - ebase);
    int idx = j * 256 + threadIdx.x;
    if (idx >= ssz) return;
    int e = ebase + idx;
    int r = row[e], c = col[e];
    float2 lab = ((const float2*)el)[e];
    u64 q0 = (u64)(unsigned)(lab.x * 65536.0f);
    u64 q1 = (u64)(unsigned)(lab.y * 65536.0f);
    u64 p = (1ULL << 54) | (q0 << 27) | q1;
    u64 oR = atomicAdd(&packR[(size_t)s * N + r], p);
    u64 oC = atomicAdd(&packC[(size_t)s * N + c], p);
    rankR[e] = (u8)(oR >> 54);
    rankC[e] = (u8)(oC >> 54);
}

// ---------------------------------------------------------------------------
// K2: per-shard segment allocation (16 scans) + compact CSR offsets (2 more
// scans). ONE parallel atomic round per block on 18 line-padded counters.
// curX[s][n] = absolute START of (shard,node) segment (never advanced).
// ---------------------------------------------------------------------------
__global__ __launch_bounds__(256) void k_prep(
    const u64* __restrict__ packR, const u64* __restrict__ packC,
    int* __restrict__ curR, int* __restrict__ curC,
    u64* __restrict__ degpackR, u64* __restrict__ degpackC,
    int* __restrict__ off_row, int* __restrict__ off_col,
    float* __restrict__ stats, int* __restrict__ gcur, int N, int SH_SZ)
{
    __shared__ int lds_tot[4][18];
    __shared__ int lds_base[4][18];

    int n = blockIdx.x * 256 + threadIdx.x;
    int lane = threadIdx.x & 63;
    int wv = threadIdx.x >> 6;
    const u64 LOW54 = (1ULL << 54) - 1;
    int cr[SH], cc[SH], psR[SH], psC[SH];
    u64 TR = 0, TC = 0;
    #pragma unroll
    for (int s = 0; s < SH; ++s) {
        u64 pR = (n < N) ? packR[(size_t)s * N + n] : 0;
        u64 pC = (n < N) ? packC[(size_t)s * N + n] : 0;
        cr[s] = (int)(pR >> 54); TR += pR & LOW54;
        cc[s] = (int)(pC >> 54); TC += pC & LOW54;
    }
    int tr = 0, tc = 0;
    #pragma unroll
    for (int s = 0; s < SH; ++s) { tr += cr[s]; tc += cc[s]; }

    #pragma unroll
    for (int s = 0; s < SH; ++s) {
        int ps = cr[s];
        #pragma unroll
        for (int d2 = 1; d2 < 64; d2 <<= 1) { int t2 = __shfl_up(ps, d2); if (lane >= d2) ps += t2; }
        psR[s] = ps;
        int ps2 = cc[s];
        #pragma unroll
        for (int d2 = 1; d2 < 64; d2 <<= 1) { int t2 = __shfl_up(ps2, d2); if (lane >= d2) ps2 += t2; }
        psC[s] = ps2;
        if (lane == 63) { lds_tot[wv][s] = ps; lds_tot[wv][8 + s] = ps2; }
    }
    int psT = tr, psU = tc;
    #pragma unroll
    for (int d2 = 1; d2 < 64; d2 <<= 1) {
        int t2 = __shfl_up(psT, d2);
        int t3 = __shfl_up(psU, d2);
        if (lane >= d2) { psT += t2; psU += t3; }
    }
    if (lane == 63) { lds_tot[wv][16] = psT; lds_tot[wv][17] = psU; }
    __syncthreads();
    if (wv == 0 && lane < 18) {
        int t0 = lds_tot[0][lane], t1 = lds_tot[1][lane],
            t2 = lds_tot[2][lane], t3 = lds_tot[3][lane];
        int gb = atomicAdd(&gcur[lane * 32], t0 + t1 + t2 + t3);
        lds_base[0][lane] = gb;
        lds_base[1][lane] = gb + t0;
        lds_base[2][lane] = gb + t0 + t1;
        lds_base[3][lane] = gb + t0 + t1 + t2;
    }
    __syncthreads();

    if (n < N) {
        u64 dpR = 0, dpC = 0;
        #pragma unroll
        for (int s = 0; s < SH; ++s) {
            curR[(size_t)s * N + n] = s * SH_SZ + lds_base[wv][s]     + psR[s] - cr[s];
            curC[(size_t)s * N + n] = s * SH_SZ + lds_base[wv][8 + s] + psC[s] - cc[s];
            dpR |= ((u64)cr[s]) << (8 * s);
            dpC |= ((u64)cc[s]) << (8 * s);
        }
        degpackR[n] = dpR;
        degpackC[n] = dpC;
        off_row[n] = lds_base[wv][16] + psT - tr;
        off_col[n] = lds_base[wv][17] + psU - tc;
        const u64 M27 = (1ULL << 27) - 1;
        const float qs = 1.0f / 65536.0f;
        float sr0 = (float)((TR >> 27) & M27) * qs;
        float sr1 = (float)(TR & M27) * qs;
        float sc0 = (float)((TC >> 27) & M27) * qs;
        float sc1 = (float)(TC & M27) * qs;
        float ir = 1.0f / fmaxf((float)tr, 1.0f);
        float ic = 1.0f / fmaxf((float)tc, 1.0f);
        float* sN = stats + (size_t)n * 8;
        sN[0] = ir;        sN[1] = ic;
        sN[2] = sr0 * ir;  sN[3] = sr1 * ir;
        sN[4] = sc0 * ic;  sN[5] = sc1 * ic;
        sN[6] = (float)tr; sN[7] = (float)tc;
    }
}

// ---------------------------------------------------------------------------
// K3: ATOMIC-FREE sharded fill: slot = segment_start (cur, scattered XCD-local
// read) + precomputed rank. Scattered stores stay XCD-local.
// ---------------------------------------------------------------------------
__global__ __launch_bounds__(256) void k_fill(
    const int* __restrict__ row, const int* __restrict__ col,
    const u8* __restrict__ rankR, const u8* __restrict__ rankC,
    const int* __restrict__ curR, const int* __restrict__ curC,
    int* __restrict__ stageR, int* __restrict__ stageC, int E, int N, int SH_SZ)
{
    int s = blockIdx.x & (SH - 1);
    int j = blockIdx.x >> 3;
    int ebase = s * SH_SZ;
    int ssz = min(SH_SZ, E - ebase);
    int idx = j * 256 + threadIdx.x;
    if (idx >= ssz) return;
    int e = ebase + idx;
    int r = row[e], c = col[e];
    stageR[curR[(size_t)s * N + r] + rankR[e]] = c;
    stageC[curC[(size_t)s * N + c] + rankC[e]] = r;
}

// ---------------------------------------------------------------------------
// K3.5: compact the 8 sharded segments per node into a true CSR.
// cur = segment START now -> src = cur[s] + (k - p[s]).
// ---------------------------------------------------------------------------
__global__ __launch_bounds__(256) void k_reorder(
    const int* __restrict__ stageR, const int* __restrict__ stageC,
    const int* __restrict__ curR, const int* __restrict__ curC,
    const u64* __restrict__ degpackR, const u64* __restrict__ degpackC,
    const int* __restrict__ off_row, const int* __restrict__ off_col,
    int* __restrict__ nbrR, int* __restrict__ nbrC, int N)
{
    int n = blockIdx.x * 4 + (threadIdx.x >> 6);
    if (n >= N) return;
    int lane = threadIdx.x & 63;

    {
        u64 dp = degpackR[n];
        int d[SH], p[SH], st[SH];
        #pragma unroll
        for (int s = 0; s < SH; ++s) d[s] = (int)((dp >> (8 * s)) & 255);
        p[0] = 0;
        #pragma unroll
        for (int s = 1; s < SH; ++s) p[s] = p[s - 1] + d[s - 1];
        int deg = p[SH - 1] + d[SH - 1];
        #pragma unroll
        for (int s = 0; s < SH; ++s)
            st[s] = curR[(size_t)s * N + n] - p[s];
        int base = off_row[n];
        for (int k = lane; k < deg; k += 64) {
            int src = st[0] + k;
            #pragma unroll
            for (int s = 1; s < SH; ++s)
                src = (k >= p[s]) ? st[s] + k : src;
            nbrR[base + k] = stageR[src];
        }
    }
    {
        u64 dp = degpackC[n];
        int d[SH], p[SH], st[SH];
        #pragma unroll
        for (int s = 0; s < SH; ++s) d[s] = (int)((dp >> (8 * s)) & 255);
        p[0] = 0;
        #pragma unroll
        for (int s = 1; s < SH; ++s) p[s] = p[s - 1] + d[s - 1];
        int deg = p[SH - 1] + d[SH - 1];
        #pragma unroll
        for (int s = 0; s < SH; ++s)
            st[s] = curC[(size_t)s * N + n] - p[s];
        int base = off_col[n];
        for (int k = lane; k < deg; k += 64) {
            int src = st[0] + k;
            #pragma unroll
            for (int s = 1; s < SH; ++s)
                src = (k >= p[s]) ? st[s] + k : src;
            nbrC[base + k] = stageC[src];
        }
    }
}

// ---------------------------------------------------------------------------
// K4: fused layer, compact CSR + bf16. 512 threads, 16 nodes/block, 2 nodes/
// wave. Gather: R and C sides interleaved + 2-deep unroll = 4 independent
// idx->row load chains in flight per iteration (k+=8). lane=(grp,c4), 8B/lane.
// Phase B: h[128] @ W (f32 LDS) + rank-2 opinion epilogue.
// ---------------------------------------------------------------------------
__global__ __launch_bounds__(512) void k_layer(
    const u16* __restrict__ xb,
    const int* __restrict__ off_row, const int* __restrict__ off_col,
    const int* __restrict__ nbrR, const int* __restrict__ nbrC,
    const float* __restrict__ stats,
    const float* __restrict__ Ttw,   // [4][64]
    const float* __restrict__ W,     // [256][64]
    const float* __restrict__ b,     // [64]
    u16* __restrict__ yb, float* __restrict__ yf, int N)
{
    __shared__ float4 hs4[16][32];
    __shared__ float  Ws[128 * 64];

    const uint2* xb2 = (const uint2*)xb;

    int t    = threadIdx.x;
    int lane = t & 63;
    int wv   = t >> 6;
    int c4   = lane & 15;
    int grp  = lane >> 4;
    int base = blockIdx.x * 16;

    float sf[2][4];

    #pragma unroll
    for (int i = 0; i < 2; ++i) {
        int loc = wv * 2 + i;
        int n   = base + loc;
        float4 aR = make_float4(0.f, 0.f, 0.f, 0.f);
        float4 aC = make_float4(0.f, 0.f, 0.f, 0.f);
        float ir = 0.f, ic = 0.f;
        sf[i][0] = sf[i][1] = sf[i][2] = sf[i][3] = 0.f;
        if (n < N) {
            const float4* st = (const float4*)(stats + (size_t)n * 8);
            float4 sA = st[0];
            float4 sB = st[1];
            ir = sA.x; ic = sA.y;
            sf[i][0] = sA.z; sf[i][1] = sA.w;
            sf[i][2] = sB.x; sf[i][3] = sB.y;
            int dR = (int)sB.z, dC = (int)sB.w;
            int sR = off_row[n], sC = off_col[n];
            int m = max(dR, dC);
            for (int k = 0; k < m; k += 8) {
                int k0 = k + grp, k1 = k + 4 + grp;
                bool pR0 = k0 < dR, pR1 = k1 < dR;
                bool pC0 = k0 < dC, pC1 = k1 < dC;
                // 4 independent index loads
                int iR0 = nbrR[pR0 ? sR + k0 : 0];
                int iR1 = nbrR[pR1 ? sR + k1 : 0];
                int iC0 = nbrC[pC0 ? sC + k0 : 0];
                int iC1 = nbrC[pC1 ? sC + k1 : 0];
                // 4 independent row loads
                uint2 vR0 = xb2[(size_t)iR0 * 16 + c4];
                uint2 vR1 = xb2[(size_t)iR1 * 16 + c4];
                uint2 vC0 = xb2[(size_t)iC0 * 16 + c4];
                uint2 vC1 = xb2[(size_t)iC1 * 16 + c4];
                if (pR0) {
                    aR.x += uaf(vR0.x << 16); aR.y += uaf(vR0.x & 0xffff0000u);
                    aR.z += uaf(vR0.y << 16); aR.w += uaf(vR0.y & 0xffff0000u);
                }
                if (pR1) {
                    aR.x += uaf(vR1.x << 16); aR.y += uaf(vR1.x & 0xffff0000u);
                    aR.z += uaf(vR1.y << 16); aR.w += uaf(vR1.y & 0xffff0000u);
                }
                if (pC0) {
                    aC.x += uaf(vC0.x << 16); aC.y += uaf(vC0.x & 0xffff0000u);
                    aC.z += uaf(vC0.y << 16); aC.w += uaf(vC0.y & 0xffff0000u);
                }
                if (pC1) {
                    aC.x += uaf(vC1.x << 16); aC.y += uaf(vC1.x & 0xffff0000u);
                    aC.z += uaf(vC1.y << 16); aC.w += uaf(vC1.y & 0xffff0000u);
                }
            }
        }
        #pragma unroll
        for (int o = 16; o < 64; o <<= 1) {
            aR.x += __shfl_xor(aR.x, o); aR.y += __shfl_xor(aR.y, o);
            aR.z += __shfl_xor(aR.z, o); aR.w += __shfl_xor(aR.w, o);
            aC.x += __shfl_xor(aC.x, o); aC.y += __shfl_xor(aC.y, o);
            aC.z += __shfl_xor(aC.z, o); aC.w += __shfl_xor(aC.w, o);
        }
        if (grp == 0) {
            hs4[loc][c4]      = make_float4(aR.x * ir, aR.y * ir, aR.z * ir, aR.w * ir);
            hs4[loc][16 + c4] = make_float4(aC.x * ic, aC.y * ic, aC.z * ic, aC.w * ic);
        }
    }

    __syncthreads();
    #pragma unroll
    for (int i = 0; i < 16; ++i) {
        int L = i * 512 + t;
        Ws[L] = W[L + ((L < 4096) ? 0 : 4096)];
    }
    __syncthreads();

    const float* hsf = (const float*)hs4;
    int r0 = (wv * 2) * 128, r1 = r0 + 128;
    float a0 = 0.f, a1 = 0.f;
    #pragma unroll 8
    for (int j = 0; j < 128; ++j) {
        float wj = Ws[j * 64 + lane];
        a0 += hsf[r0 + j] * wj;
        a1 += hsf[r1 + j] * wj;
    }

    float tR0 = Ttw[lane],       tR1 = Ttw[64 + lane];
    float tC0 = Ttw[128 + lane], tC1 = Ttw[192 + lane];
    float bias = b[lane];
    float vv[2] = {a0, a1};
    #pragma unroll
    for (int i = 0; i < 2; ++i) {
        int n = base + wv * 2 + i;
        if (n < N) {
            float v = vv[i] + sf[i][0] * tR0 + sf[i][1] * tR1
                            + sf[i][2] * tC0 + sf[i][3] * tC1 + bias;
            v = fmaxf(v, 0.0f);
            if (yf) {
                yf[(size_t)n * D + lane] = v;
            } else {
                unsigned u = __float_as_uint(v);
                yb[(size_t)n * D + lane] = (u16)((u + 0x7fffu + ((u >> 16) & 1u)) >> 16);
            }
        }
    }
}

// ---------------------------------------------------------------------------
extern "C" void kernel_launch(void* const* d_in, const int* in_sizes, int n_in,
                              void* d_out, int out_size, void* d_ws, size_t ws_size,
                              hipStream_t stream)
{
    const float* X   = (const float*)d_in[0];
    const int*   ei  = (const int*)  d_in[1];
    const float* el  = (const float*)d_in[2];
    const float* w1  = (const float*)d_in[3];
    const float* tw1 = (const float*)d_in[4];
    const float* b1  = (const float*)d_in[5];
    const float* w2  = (const float*)d_in[6];
    const float* tw2 = (const float*)d_in[7];
    const float* b2  = (const float*)d_in[8];
    float* out = (float*)d_out;

    int N = in_sizes[0] / D;     // 50000
    int E = in_sizes[1] / 2;     // 800000
    const int* row = ei;
    const int* col = ei + E;
    int SH_SZ = (E + SH - 1) / SH;

    // Workspace (~25.6 MiB, under round-1's proven 26.8 MB).
    // pack -> stage CSR (after prep) -> h1 bf16 (after reorder) share a region.
    size_t packBytes = (size_t)2 * SH * N * sizeof(u64);
    size_t stageBytes = (size_t)2 * E * sizeof(int);
    size_t h1Bytes = (size_t)64 * N * sizeof(u16);
    if (stageBytes > packBytes) packBytes = stageBytes;
    if (h1Bytes > packBytes) packBytes = h1Bytes;

    char* wsb = (char*)d_ws;
    u64*   packR    = (u64*)wsb;                        // SH*N u64 (zeroed)
    u64*   packC    = packR + (size_t)SH * N;           // SH*N u64 (zeroed)
    int*   stageR   = (int*)wsb;                        // E ints (aliases pack)
    int*   stageC   = stageR + E;                       // E ints
    u16*   h1b      = (u16*)wsb;                        // 64N bf16 (aliases stage)
    int*   gcur     = (int*)(wsb + packBytes);          // 1024 ints line-padded (zeroed)
    int*   curR     = gcur + 1024;                      // SH*N
    int*   curC     = curR + (size_t)SH * N;            // SH*N
    u64*   degpackR = (u64*)(curC + (size_t)SH * N);    // N
    u64*   degpackC = degpackR + N;                     // N
    int*   off_row  = (int*)(degpackC + N);             // N
    int*   off_col  = off_row + N;                      // N
    float* stats    = (float*)(off_col + N);            // 8N
    float* Ttw1     = stats + (size_t)8 * N;            // 256
    float* Ttw2     = Ttw1 + 256;                       // 256
    int*   nbrR     = (int*)(Ttw2 + 256);               // E
    int*   nbrC     = nbrR + E;                         // E
    u16*   Xb       = (u16*)(nbrC + E);                 // 64N bf16
    u8*    rankR    = (u8*)(Xb + (size_t)64 * N);       // E
    u8*    rankC    = rankR + E;                        // E

    (void)hipMemsetAsync(packR, 0, (size_t)2 * SH * N * sizeof(u64), stream);
    (void)hipMemsetAsync(gcur, 0, 1024 * sizeof(int), stream);

    k_cvt<<<(N * 8 + 255) / 256, 256, 0, stream>>>((const float4*)X, (uint4*)Xb, N * 8);
    k_ttw<<<2, 256, 0, stream>>>(tw1, w1, Ttw1, tw2, w2, Ttw2);

    int SB = SH * ((SH_SZ + 255) / 256);
    int NB = (N + 255) / 256;
    int RB = (N + 3) / 4;
    int LB = (N + 15) / 16;

    k_count<<<SB, 256, 0, stream>>>(row, col, el, packR, packC,
                                    rankR, rankC, E, N, SH_SZ);
    k_prep<<<NB, 256, 0, stream>>>(packR, packC, curR, curC,
                                   degpackR, degpackC, off_row, off_col,
                                   stats, gcur, N, SH_SZ);
    k_fill<<<SB, 256, 0, stream>>>(row, col, rankR, rankC, curR, curC,
                                   stageR, stageC, E, N, SH_SZ);
    k_reorder<<<RB, 256, 0, stream>>>(stageR, stageC, curR, curC,
                                      degpackR, degpackC, off_row, off_col,
                                      nbrR, nbrC, N);

    // layer 1: Xb -> h1b (bf16, aliases dead stage region); layer 2 -> out f32
    k_layer<<<LB, 512, 0, stream>>>(Xb, off_row, off_col, nbrR, nbrC, stats,
                                    Ttw1, w1, b1, h1b, nullptr, N);
    k_layer<<<LB, 512, 0, stream>>>(h1b, off_row, off_col, nbrR, nbrC, stats,
                                    Ttw2, w2, b2, nullptr, out, N);
}